// Round 10
// baseline (489.655 us; speedup 1.0000x reference)
//
#include <hip/hip_runtime.h>

#define NPTS   1048576
#define NLEV   16
#define TSIZE  (1u << 19)
#define HMASK  (TSIZE - 1u)
#define NBUCK  32768          // 32^3 Morton buckets

typedef float f32x4 __attribute__((ext_vector_type(4)));

// floor(16 * b^l), b = 32^(1/15): f32-correct values
__device__ __constant__ float NLF_TAB[16] = {
    16.f, 20.f, 25.f, 32.f, 40.f, 50.f, 64.f, 80.f,
    101.f, 128.f, 161.f, 203.f, 256.f, 322.f, 406.f, 512.f};

__device__ __forceinline__ unsigned spread5(unsigned x) {
    x &= 0x1F;
    x = (x | (x << 8)) & 0x100F;
    x = (x | (x << 4)) & 0x10C3;
    x = (x | (x << 2)) & 0x1249;
    return x;
}

__device__ __forceinline__ unsigned morton_key(float u0, float u1, float u2) {
    unsigned k0 = min(31u, (unsigned)(u0 * 32.0f));
    unsigned k1 = min(31u, (unsigned)(u1 * 32.0f));
    unsigned k2 = min(31u, (unsigned)(u2 * 32.0f));
    return (spread5(k0) << 2) | (spread5(k1) << 1) | spread5(k2);
}

__device__ __forceinline__ void uvw(float x0, float x1, float x2,
                                    float* u0, float* u1, float* u2) {
    const float mn = -1.5f, mx = 1.5f, rng = 3.0f;
    *u0 = (fminf(fmaxf(x0, mn), mx) - mn) / rng;
    *u1 = (fminf(fmaxf(x1, mn), mx) - mn) / rng;
    *u2 = (fminf(fmaxf(x2, mn), mx) - mn) / rng;
}

__device__ __forceinline__ void level_lerp(
    float x0, float x1, float x2, float u0, float u1, float u2,
    float Nl, const float2* __restrict__ tab, float* r0, float* r1)
{
#pragma clang fp contract(off)
    const float mn = -1.5f, rng = 3.0f;
    const float box = rng / Nl;

    int g0 = (int)floorf(u0 * Nl);
    int g1 = (int)floorf(u1 * Nl);
    int g2 = (int)floorf(u2 * Nl);

    float vmin0 = (float)g0 * box + mn;
    float vmin1 = (float)g1 * box + mn;
    float vmin2 = (float)g2 * box + mn;

    float den0 = (vmin0 + box) - vmin0;
    float den1 = (vmin1 + box) - vmin1;
    float den2 = (vmin2 + box) - vmin2;

    float wx = (x0 - vmin0) / den0;
    float wy = (x1 - vmin1) / den1;
    float wz = (x2 - vmin2) / den2;

    unsigned hx0 = (unsigned)g0;
    unsigned hx1 = (unsigned)(g0 + 1);
    unsigned hy0 = (unsigned)g1       * 2654435761u;
    unsigned hy1 = (unsigned)(g1 + 1) * 2654435761u;
    unsigned hz0 = (unsigned)g2       * 805459861u;
    unsigned hz1 = (unsigned)(g2 + 1) * 805459861u;

    float2 e000 = tab[(hx0 ^ hy0 ^ hz0) & HMASK];
    float2 e001 = tab[(hx0 ^ hy0 ^ hz1) & HMASK];
    float2 e010 = tab[(hx0 ^ hy1 ^ hz0) & HMASK];
    float2 e011 = tab[(hx0 ^ hy1 ^ hz1) & HMASK];
    float2 e100 = tab[(hx1 ^ hy0 ^ hz0) & HMASK];
    float2 e101 = tab[(hx1 ^ hy0 ^ hz1) & HMASK];
    float2 e110 = tab[(hx1 ^ hy1 ^ hz0) & HMASK];
    float2 e111 = tab[(hx1 ^ hy1 ^ hz1) & HMASK];

    float omx = 1.0f - wx, omy = 1.0f - wy, omz = 1.0f - wz;
    {
        float c00 = e000.x * omx + e100.x * wx;
        float c01 = e001.x * omx + e101.x * wx;
        float c10 = e010.x * omx + e110.x * wx;
        float c11 = e011.x * omx + e111.x * wx;
        float c0  = c00 * omy + c10 * wy;
        float c1  = c01 * omy + c11 * wy;
        *r0 = c0 * omz + c1 * wz;
    }
    {
        float c00 = e000.y * omx + e100.y * wx;
        float c01 = e001.y * omx + e101.y * wx;
        float c10 = e010.y * omx + e110.y * wx;
        float c11 = e011.y * omx + e111.y * wx;
        float c0  = c00 * omy + c10 * wy;
        float c1  = c01 * omy + c11 * wy;
        *r1 = c0 * omz + c1 * wz;
    }
}

// Same math but x-corner pairs fetched as one aligned float4 when g0 even:
// h(g0+1) = h(g0)^1 for even g0, and {idx&~1, idx|1} share a 16B-aligned f4.
__device__ __forceinline__ void level_lerp_pair(
    float x0, float x1, float x2, float u0, float u1, float u2,
    float Nl, const float2* __restrict__ tab, float* r0, float* r1)
{
#pragma clang fp contract(off)
    const float mn = -1.5f, rng = 3.0f;
    const float box = rng / Nl;

    int g0 = (int)floorf(u0 * Nl);
    int g1 = (int)floorf(u1 * Nl);
    int g2 = (int)floorf(u2 * Nl);

    float vmin0 = (float)g0 * box + mn;
    float vmin1 = (float)g1 * box + mn;
    float vmin2 = (float)g2 * box + mn;

    float den0 = (vmin0 + box) - vmin0;
    float den1 = (vmin1 + box) - vmin1;
    float den2 = (vmin2 + box) - vmin2;

    float wx = (x0 - vmin0) / den0;
    float wy = (x1 - vmin1) / den1;
    float wz = (x2 - vmin2) / den2;

    unsigned m00 = ((unsigned)g1       * 2654435761u) ^ ((unsigned)g2       * 805459861u);
    unsigned m01 = ((unsigned)g1       * 2654435761u) ^ ((unsigned)(g2 + 1) * 805459861u);
    unsigned m10 = ((unsigned)(g1 + 1) * 2654435761u) ^ ((unsigned)g2       * 805459861u);
    unsigned m11 = ((unsigned)(g1 + 1) * 2654435761u) ^ ((unsigned)(g2 + 1) * 805459861u);

    unsigned i000 = ((unsigned)g0 ^ m00) & HMASK;
    unsigned i001 = ((unsigned)g0 ^ m01) & HMASK;
    unsigned i010 = ((unsigned)g0 ^ m10) & HMASK;
    unsigned i011 = ((unsigned)g0 ^ m11) & HMASK;

    const f32x4* tab4 = (const f32x4*)tab;
    f32x4 q00 = tab4[i000 >> 1];
    f32x4 q01 = tab4[i001 >> 1];
    f32x4 q10 = tab4[i010 >> 1];
    f32x4 q11 = tab4[i011 >> 1];

    bool odd = (g0 & 1) != 0;
    float2 f100, f101, f110, f111;
    if (odd) {
        unsigned x1h = (unsigned)(g0 + 1);
        f100 = tab[(x1h ^ m00) & HMASK];
        f101 = tab[(x1h ^ m01) & HMASK];
        f110 = tab[(x1h ^ m10) & HMASK];
        f111 = tab[(x1h ^ m11) & HMASK];
    }

    float2 e000, p000, e001, p001, e010, p010, e011, p011;
    {
        bool hi00 = i000 & 1, hi01 = i001 & 1, hi10 = i010 & 1, hi11 = i011 & 1;
        e000 = hi00 ? make_float2(q00.z, q00.w) : make_float2(q00.x, q00.y);
        p000 = hi00 ? make_float2(q00.x, q00.y) : make_float2(q00.z, q00.w);
        e001 = hi01 ? make_float2(q01.z, q01.w) : make_float2(q01.x, q01.y);
        p001 = hi01 ? make_float2(q01.x, q01.y) : make_float2(q01.z, q01.w);
        e010 = hi10 ? make_float2(q10.z, q10.w) : make_float2(q10.x, q10.y);
        p010 = hi10 ? make_float2(q10.x, q10.y) : make_float2(q10.z, q10.w);
        e011 = hi11 ? make_float2(q11.z, q11.w) : make_float2(q11.x, q11.y);
        p011 = hi11 ? make_float2(q11.x, q11.y) : make_float2(q11.z, q11.w);
    }

    float2 e100 = odd ? f100 : p000;
    float2 e101 = odd ? f101 : p001;
    float2 e110 = odd ? f110 : p010;
    float2 e111 = odd ? f111 : p011;

    float omx = 1.0f - wx, omy = 1.0f - wy, omz = 1.0f - wz;
    {
        float c00 = e000.x * omx + e100.x * wx;
        float c01 = e001.x * omx + e101.x * wx;
        float c10 = e010.x * omx + e110.x * wx;
        float c11 = e011.x * omx + e111.x * wx;
        float c0  = c00 * omy + c10 * wy;
        float c1  = c01 * omy + c11 * wy;
        *r0 = c0 * omz + c1 * wz;
    }
    {
        float c00 = e000.y * omx + e100.y * wx;
        float c01 = e001.y * omx + e101.y * wx;
        float c10 = e010.y * omx + e110.y * wx;
        float c11 = e011.y * omx + e111.y * wx;
        float c0  = c00 * omy + c10 * wy;
        float c1  = c01 * omy + c11 * wy;
        *r1 = c0 * omz + c1 * wz;
    }
}

// ---------- sort kernels ----------

__global__ __launch_bounds__(256)
void hist_kernel(const float* __restrict__ xin, unsigned* __restrict__ hist)
{
    int p = blockIdx.x * 256 + threadIdx.x;
    if (p >= NPTS) return;
    float x0 = xin[3 * p], x1 = xin[3 * p + 1], x2 = xin[3 * p + 2];
    float u0, u1, u2; uvw(x0, x1, x2, &u0, &u1, &u2);
    atomicAdd(&hist[morton_key(u0, u1, u2)], 1u);
}

__global__ __launch_bounds__(1024)
void scan_kernel(unsigned* __restrict__ hist, unsigned* __restrict__ cursor)
{
    __shared__ unsigned part[1024];
    int t = threadIdx.x;
    unsigned local[32];
    unsigned s = 0;
#pragma unroll
    for (int i = 0; i < 32; ++i) { local[i] = hist[t * 32 + i]; s += local[i]; }
    part[t] = s;
    __syncthreads();
    for (int off = 1; off < 1024; off <<= 1) {
        unsigned v = (t >= off) ? part[t - off] : 0;
        __syncthreads();
        part[t] += v;
        __syncthreads();
    }
    unsigned base = (t == 0) ? 0u : part[t - 1];
#pragma unroll
    for (int i = 0; i < 32; ++i) {
        cursor[t * 32 + i] = base;
        base += local[i];
    }
}

__global__ __launch_bounds__(256)
void scatter_kernel(const float* __restrict__ xin,
                    unsigned* __restrict__ cursor,
                    unsigned* __restrict__ sidx,
                    float4* __restrict__ sx4)
{
    int p = blockIdx.x * 256 + threadIdx.x;
    if (p >= NPTS) return;
    float x0 = xin[3 * p], x1 = xin[3 * p + 1], x2 = xin[3 * p + 2];
    float u0, u1, u2; uvw(x0, x1, x2, &u0, &u1, &u2);
    unsigned pos = atomicAdd(&cursor[morton_key(u0, u1, u2)], 1u);
    sidx[pos] = (unsigned)p;
    sx4[pos] = make_float4(x0, x1, x2, 0.0f);
}

// ---------- compute kernels ----------

__global__ __launch_bounds__(256)
void coarse_sorted(const unsigned* __restrict__ sidx,
                   const float4* __restrict__ sx4,
                   const float* __restrict__ tables,
                   float* __restrict__ out)
{
#pragma clang fp contract(off)
    int s = blockIdx.x * 256 + threadIdx.x;
    if (s >= NPTS) return;
    unsigned p = sidx[s];
    float4 xv = sx4[s];
    float u0, u1, u2; uvw(xv.x, xv.y, xv.z, &u0, &u1, &u2);

    float res[16];
#pragma unroll
    for (int l = 0; l < 8; ++l) {
        const float2* tab = (const float2*)tables + (size_t)l * TSIZE;
        level_lerp(xv.x, xv.y, xv.z, u0, u1, u2, NLF_TAB[l], tab,
                   &res[2 * l], &res[2 * l + 1]);
    }

    float4* orow = (float4*)(out + (size_t)p * 32);
#pragma unroll
    for (int i = 0; i < 4; ++i)
        orow[i] = make_float4(res[4 * i + 0], res[4 * i + 1],
                              res[4 * i + 2], res[4 * i + 3]);
}

__global__ __launch_bounds__(256)
void mid_sorted(const unsigned* __restrict__ sidx,
                const float4* __restrict__ sx4,
                const float* __restrict__ tables,
                float* __restrict__ out)
{
#pragma clang fp contract(off)
    int s = blockIdx.x * 256 + threadIdx.x;
    if (s >= NPTS) return;
    unsigned p = sidx[s];
    float4 xv = sx4[s];
    float u0, u1, u2; uvw(xv.x, xv.y, xv.z, &u0, &u1, &u2);

    float r[4];
    {
        const float2* tab = (const float2*)tables + (size_t)8 * TSIZE;
        level_lerp(xv.x, xv.y, xv.z, u0, u1, u2, NLF_TAB[8], tab, &r[0], &r[1]);
    }
    {
        const float2* tab = (const float2*)tables + (size_t)9 * TSIZE;
        level_lerp(xv.x, xv.y, xv.z, u0, u1, u2, NLF_TAB[9], tab, &r[2], &r[3]);
    }
    *(float4*)(out + (size_t)p * 32 + 16) = make_float4(r[0], r[1], r[2], r[3]);
}

// One fine level L (10..15), original order, f4 x-pair line-sharing.
template<int L, bool WRITE_MASK>
__global__ __launch_bounds__(256)
void fine_kernel(const float* __restrict__ xin,
                 const float* __restrict__ tables,
                 float* __restrict__ out)
{
#pragma clang fp contract(off)
    int p = blockIdx.x * 256 + threadIdx.x;
    if (p >= NPTS) return;
    float x0 = xin[3 * p], x1 = xin[3 * p + 1], x2 = xin[3 * p + 2];
    float u0, u1, u2; uvw(x0, x1, x2, &u0, &u1, &u2);

    const float2* tab = (const float2*)tables + (size_t)L * TSIZE;
    float r0, r1;
    level_lerp_pair(x0, x1, x2, u0, u1, u2, NLF_TAB[L], tab, &r0, &r1);
    *(float2*)(out + (size_t)p * 32 + 2 * L) = make_float2(r0, r1);

    if (WRITE_MASK) {
        const float mn = -1.5f, mx = 1.5f;
        float keep = (x0 >= mn && x0 <= mx &&
                      x1 >= mn && x1 <= mx &&
                      x2 >= mn && x2 <= mx) ? 1.0f : 0.0f;
        out[(size_t)NPTS * 32 + p] = keep;
    }
}

// ---------- fallback (no-workspace path) ----------

__global__ __launch_bounds__(256)
void coarse_kernel(const float* __restrict__ xin,
                   const float* __restrict__ tables,
                   float* __restrict__ out)
{
#pragma clang fp contract(off)
    int p = blockIdx.x * 256 + threadIdx.x;
    if (p >= NPTS) return;
    float x0 = xin[3 * p], x1 = xin[3 * p + 1], x2 = xin[3 * p + 2];
    float u0, u1, u2; uvw(x0, x1, x2, &u0, &u1, &u2);

    float res[16];
#pragma unroll
    for (int l = 0; l < 8; ++l) {
        const float2* tab = (const float2*)tables + (size_t)l * TSIZE;
        level_lerp(x0, x1, x2, u0, u1, u2, NLF_TAB[l], tab,
                   &res[2 * l], &res[2 * l + 1]);
    }
    float4* orow = (float4*)(out + (size_t)p * 32);
#pragma unroll
    for (int i = 0; i < 4; ++i)
        orow[i] = make_float4(res[4 * i + 0], res[4 * i + 1],
                              res[4 * i + 2], res[4 * i + 3]);
}

extern "C" void kernel_launch(void* const* d_in, const int* in_sizes, int n_in,
                              void* d_out, int out_size, void* d_ws, size_t ws_size,
                              hipStream_t stream) {
    const float* x      = (const float*)d_in[0];
    const float* tables = (const float*)d_in[2];
    float* out = (float*)d_out;

    int n = in_sizes[0] / 3;           // 1048576
    int blocks = (n + 255) / 256;      // 4096

    const size_t HIST_B   = (size_t)NBUCK * 4;              // 128 KB
    const size_t SIDX_OFF = 131072;                         // aligned
    const size_t SX4_OFF  = SIDX_OFF + (size_t)NPTS * 4;    // +4 MB
    const size_t NEEDED   = SX4_OFF + (size_t)NPTS * 16;    // ≈ 20.2 MB

    if (ws_size >= NEEDED) {
        unsigned* hist = (unsigned*)d_ws;
        unsigned* sidx = (unsigned*)((char*)d_ws + SIDX_OFF);
        float4*   sx4  = (float4*)((char*)d_ws + SX4_OFF);

        hipMemsetAsync(hist, 0, HIST_B, stream);
        hist_kernel<<<blocks, 256, 0, stream>>>(x, hist);
        scan_kernel<<<1, 1024, 0, stream>>>(hist, hist);  // in-place -> cursors
        scatter_kernel<<<blocks, 256, 0, stream>>>(x, hist, sidx, sx4);

        coarse_sorted<<<blocks, 256, 0, stream>>>(sidx, sx4, tables, out);
        mid_sorted<<<blocks, 256, 0, stream>>>(sidx, sx4, tables, out);
    } else {
        coarse_kernel<<<blocks, 256, 0, stream>>>(x, tables, out);
        fine_kernel< 8, false><<<blocks, 256, 0, stream>>>(x, tables, out);
        fine_kernel< 9, false><<<blocks, 256, 0, stream>>>(x, tables, out);
    }

    fine_kernel<10, true ><<<blocks, 256, 0, stream>>>(x, tables, out);
    fine_kernel<11, false><<<blocks, 256, 0, stream>>>(x, tables, out);
    fine_kernel<12, false><<<blocks, 256, 0, stream>>>(x, tables, out);
    fine_kernel<13, false><<<blocks, 256, 0, stream>>>(x, tables, out);
    fine_kernel<14, false><<<blocks, 256, 0, stream>>>(x, tables, out);
    fine_kernel<15, false><<<blocks, 256, 0, stream>>>(x, tables, out);
}

// Round 11
// 444.654 us; speedup vs baseline: 1.1012x; 1.1012x over previous
//
#include <hip/hip_runtime.h>

#define NPTS   1048576
#define NLEV   16
#define TSIZE  (1u << 19)
#define HMASK  (TSIZE - 1u)
#define NBUCK  32768          // 32^3 Morton buckets

// floor(16 * b^l), b = 32^(1/15): f32-correct values
__device__ __constant__ float NLF_TAB[16] = {
    16.f, 20.f, 25.f, 32.f, 40.f, 50.f, 64.f, 80.f,
    101.f, 128.f, 161.f, 203.f, 256.f, 322.f, 406.f, 512.f};

__device__ __forceinline__ unsigned spread5(unsigned x) {
    x &= 0x1F;
    x = (x | (x << 8)) & 0x100F;
    x = (x | (x << 4)) & 0x10C3;
    x = (x | (x << 2)) & 0x1249;
    return x;
}

__device__ __forceinline__ unsigned morton_key(float u0, float u1, float u2) {
    unsigned k0 = min(31u, (unsigned)(u0 * 32.0f));
    unsigned k1 = min(31u, (unsigned)(u1 * 32.0f));
    unsigned k2 = min(31u, (unsigned)(u2 * 32.0f));
    return (spread5(k0) << 2) | (spread5(k1) << 1) | spread5(k2);
}

__device__ __forceinline__ void uvw(float x0, float x1, float x2,
                                    float* u0, float* u1, float* u2) {
    const float mn = -1.5f, mx = 1.5f, rng = 3.0f;
    *u0 = (fminf(fmaxf(x0, mn), mx) - mn) / rng;
    *u1 = (fminf(fmaxf(x1, mn), mx) - mn) / rng;
    *u2 = (fminf(fmaxf(x2, mn), mx) - mn) / rng;
}

__device__ __forceinline__ void level_lerp(
    float x0, float x1, float x2, float u0, float u1, float u2,
    float Nl, const float2* __restrict__ tab, float* r0, float* r1)
{
#pragma clang fp contract(off)
    const float mn = -1.5f, rng = 3.0f;
    const float box = rng / Nl;

    int g0 = (int)floorf(u0 * Nl);
    int g1 = (int)floorf(u1 * Nl);
    int g2 = (int)floorf(u2 * Nl);

    float vmin0 = (float)g0 * box + mn;
    float vmin1 = (float)g1 * box + mn;
    float vmin2 = (float)g2 * box + mn;

    float den0 = (vmin0 + box) - vmin0;
    float den1 = (vmin1 + box) - vmin1;
    float den2 = (vmin2 + box) - vmin2;

    float wx = (x0 - vmin0) / den0;
    float wy = (x1 - vmin1) / den1;
    float wz = (x2 - vmin2) / den2;

    unsigned hx0 = (unsigned)g0;
    unsigned hx1 = (unsigned)(g0 + 1);
    unsigned hy0 = (unsigned)g1       * 2654435761u;
    unsigned hy1 = (unsigned)(g1 + 1) * 2654435761u;
    unsigned hz0 = (unsigned)g2       * 805459861u;
    unsigned hz1 = (unsigned)(g2 + 1) * 805459861u;

    float2 e000 = tab[(hx0 ^ hy0 ^ hz0) & HMASK];
    float2 e001 = tab[(hx0 ^ hy0 ^ hz1) & HMASK];
    float2 e010 = tab[(hx0 ^ hy1 ^ hz0) & HMASK];
    float2 e011 = tab[(hx0 ^ hy1 ^ hz1) & HMASK];
    float2 e100 = tab[(hx1 ^ hy0 ^ hz0) & HMASK];
    float2 e101 = tab[(hx1 ^ hy0 ^ hz1) & HMASK];
    float2 e110 = tab[(hx1 ^ hy1 ^ hz0) & HMASK];
    float2 e111 = tab[(hx1 ^ hy1 ^ hz1) & HMASK];

    float omx = 1.0f - wx, omy = 1.0f - wy, omz = 1.0f - wz;
    {
        float c00 = e000.x * omx + e100.x * wx;
        float c01 = e001.x * omx + e101.x * wx;
        float c10 = e010.x * omx + e110.x * wx;
        float c11 = e011.x * omx + e111.x * wx;
        float c0  = c00 * omy + c10 * wy;
        float c1  = c01 * omy + c11 * wy;
        *r0 = c0 * omz + c1 * wz;
    }
    {
        float c00 = e000.y * omx + e100.y * wx;
        float c01 = e001.y * omx + e101.y * wx;
        float c10 = e010.y * omx + e110.y * wx;
        float c11 = e011.y * omx + e111.y * wx;
        float c0  = c00 * omy + c10 * wy;
        float c1  = c01 * omy + c11 * wy;
        *r1 = c0 * omz + c1 * wz;
    }
}

// ---------- sort kernels ----------

__global__ __launch_bounds__(1024)
void scan_kernel(unsigned* __restrict__ hist, unsigned* __restrict__ cursor)
{
    __shared__ unsigned part[1024];
    int t = threadIdx.x;
    unsigned local[32];
    unsigned s = 0;
#pragma unroll
    for (int i = 0; i < 32; ++i) { local[i] = hist[t * 32 + i]; s += local[i]; }
    part[t] = s;
    __syncthreads();
    for (int off = 1; off < 1024; off <<= 1) {
        unsigned v = (t >= off) ? part[t - off] : 0;
        __syncthreads();
        part[t] += v;
        __syncthreads();
    }
    unsigned base = (t == 0) ? 0u : part[t - 1];
#pragma unroll
    for (int i = 0; i < 32; ++i) {
        cursor[t * 32 + i] = base;
        base += local[i];
    }
}

__global__ __launch_bounds__(256)
void scatter_kernel(const float* __restrict__ xin,
                    unsigned* __restrict__ cursor,
                    unsigned* __restrict__ sidx,
                    float4* __restrict__ sx4)
{
    int p = blockIdx.x * 256 + threadIdx.x;
    if (p >= NPTS) return;
    float x0 = xin[3 * p], x1 = xin[3 * p + 1], x2 = xin[3 * p + 2];
    float u0, u1, u2; uvw(x0, x1, x2, &u0, &u1, &u2);
    unsigned pos = atomicAdd(&cursor[morton_key(u0, u1, u2)], 1u);
    sidx[pos] = (unsigned)p;
    sx4[pos] = make_float4(x0, x1, x2, 0.0f);
}

// ---------- compute kernels ----------

// Levels 0..9 over sorted points; writes first 80B of each row.
__global__ __launch_bounds__(256)
void coarse10_sorted(const unsigned* __restrict__ sidx,
                     const float4* __restrict__ sx4,
                     const float* __restrict__ tables,
                     float* __restrict__ out)
{
#pragma clang fp contract(off)
    int s = blockIdx.x * 256 + threadIdx.x;
    if (s >= NPTS) return;
    unsigned p = sidx[s];
    float4 xv = sx4[s];
    float u0, u1, u2; uvw(xv.x, xv.y, xv.z, &u0, &u1, &u2);

    float res[20];
#pragma unroll
    for (int l = 0; l < 10; ++l) {
        const float2* tab = (const float2*)tables + (size_t)l * TSIZE;
        level_lerp(xv.x, xv.y, xv.z, u0, u1, u2, NLF_TAB[l], tab,
                   &res[2 * l], &res[2 * l + 1]);
    }

    float4* orow = (float4*)(out + (size_t)p * 32);
#pragma unroll
    for (int i = 0; i < 5; ++i)
        orow[i] = make_float4(res[4 * i + 0], res[4 * i + 1],
                              res[4 * i + 2], res[4 * i + 3]);
}

// One fine level L (10..15), original point order (coalesced 8B writes).
// FUSE_HIST: piggyback the Morton histogram on this kernel's x-read.
template<int L, bool WRITE_MASK, bool FUSE_HIST>
__global__ __launch_bounds__(256)
void fine_kernel(const float* __restrict__ xin,
                 const float* __restrict__ tables,
                 float* __restrict__ out,
                 unsigned* __restrict__ hist)
{
#pragma clang fp contract(off)
    int p = blockIdx.x * 256 + threadIdx.x;
    if (p >= NPTS) return;
    float x0 = xin[3 * p], x1 = xin[3 * p + 1], x2 = xin[3 * p + 2];
    float u0, u1, u2; uvw(x0, x1, x2, &u0, &u1, &u2);

    if (FUSE_HIST)
        atomicAdd(&hist[morton_key(u0, u1, u2)], 1u);

    const float2* tab = (const float2*)tables + (size_t)L * TSIZE;
    float r0, r1;
    level_lerp(x0, x1, x2, u0, u1, u2, NLF_TAB[L], tab, &r0, &r1);
    *(float2*)(out + (size_t)p * 32 + 2 * L) = make_float2(r0, r1);

    if (WRITE_MASK) {
        const float mn = -1.5f, mx = 1.5f;
        float keep = (x0 >= mn && x0 <= mx &&
                      x1 >= mn && x1 <= mx &&
                      x2 >= mn && x2 <= mx) ? 1.0f : 0.0f;
        out[(size_t)NPTS * 32 + p] = keep;
    }
}

// ---------- fallback (no-workspace path) ----------

__global__ __launch_bounds__(256)
void coarse_kernel(const float* __restrict__ xin,
                   const float* __restrict__ tables,
                   float* __restrict__ out)
{
#pragma clang fp contract(off)
    int p = blockIdx.x * 256 + threadIdx.x;
    if (p >= NPTS) return;
    float x0 = xin[3 * p], x1 = xin[3 * p + 1], x2 = xin[3 * p + 2];
    float u0, u1, u2; uvw(x0, x1, x2, &u0, &u1, &u2);

    float res[16];
#pragma unroll
    for (int l = 0; l < 8; ++l) {
        const float2* tab = (const float2*)tables + (size_t)l * TSIZE;
        level_lerp(x0, x1, x2, u0, u1, u2, NLF_TAB[l], tab,
                   &res[2 * l], &res[2 * l + 1]);
    }
    float4* orow = (float4*)(out + (size_t)p * 32);
#pragma unroll
    for (int i = 0; i < 4; ++i)
        orow[i] = make_float4(res[4 * i + 0], res[4 * i + 1],
                              res[4 * i + 2], res[4 * i + 3]);
}

template<int L>
__global__ __launch_bounds__(256)
void fine_plain(const float* __restrict__ xin,
                const float* __restrict__ tables,
                float* __restrict__ out)
{
#pragma clang fp contract(off)
    int p = blockIdx.x * 256 + threadIdx.x;
    if (p >= NPTS) return;
    float x0 = xin[3 * p], x1 = xin[3 * p + 1], x2 = xin[3 * p + 2];
    float u0, u1, u2; uvw(x0, x1, x2, &u0, &u1, &u2);

    const float2* tab = (const float2*)tables + (size_t)L * TSIZE;
    float r0, r1;
    level_lerp(x0, x1, x2, u0, u1, u2, NLF_TAB[L], tab, &r0, &r1);
    *(float2*)(out + (size_t)p * 32 + 2 * L) = make_float2(r0, r1);
}

extern "C" void kernel_launch(void* const* d_in, const int* in_sizes, int n_in,
                              void* d_out, int out_size, void* d_ws, size_t ws_size,
                              hipStream_t stream) {
    const float* x      = (const float*)d_in[0];
    const float* tables = (const float*)d_in[2];
    float* out = (float*)d_out;

    int n = in_sizes[0] / 3;           // 1048576
    int blocks = (n + 255) / 256;      // 4096

    const size_t HIST_B   = (size_t)NBUCK * 4;              // 128 KB
    const size_t SIDX_OFF = 131072;                         // aligned
    const size_t SX4_OFF  = SIDX_OFF + (size_t)NPTS * 4;    // +4 MB
    const size_t NEEDED   = SX4_OFF + (size_t)NPTS * 16;    // ≈ 20.2 MB

    if (ws_size >= NEEDED) {
        unsigned* hist = (unsigned*)d_ws;
        unsigned* sidx = (unsigned*)((char*)d_ws + SIDX_OFF);
        float4*   sx4  = (float4*)((char*)d_ws + SX4_OFF);

        hipMemsetAsync(hist, 0, HIST_B, stream);

        // Fines first; fine15 builds the Morton histogram on its x-read.
        fine_kernel<15, false, true ><<<blocks, 256, 0, stream>>>(x, tables, out, hist);
        fine_kernel<14, false, false><<<blocks, 256, 0, stream>>>(x, tables, out, hist);
        fine_kernel<13, false, false><<<blocks, 256, 0, stream>>>(x, tables, out, hist);
        fine_kernel<12, false, false><<<blocks, 256, 0, stream>>>(x, tables, out, hist);
        fine_kernel<11, false, false><<<blocks, 256, 0, stream>>>(x, tables, out, hist);
        fine_kernel<10, true , false><<<blocks, 256, 0, stream>>>(x, tables, out, hist);

        scan_kernel<<<1, 1024, 0, stream>>>(hist, hist);  // in-place -> cursors
        scatter_kernel<<<blocks, 256, 0, stream>>>(x, hist, sidx, sx4);
        coarse10_sorted<<<blocks, 256, 0, stream>>>(sidx, sx4, tables, out);
    } else {
        coarse_kernel<<<blocks, 256, 0, stream>>>(x, tables, out);
        fine_plain< 8><<<blocks, 256, 0, stream>>>(x, tables, out);
        fine_plain< 9><<<blocks, 256, 0, stream>>>(x, tables, out);
        fine_kernel<10, true , false><<<blocks, 256, 0, stream>>>(x, tables, out, nullptr);
        fine_plain<11><<<blocks, 256, 0, stream>>>(x, tables, out);
        fine_plain<12><<<blocks, 256, 0, stream>>>(x, tables, out);
        fine_plain<13><<<blocks, 256, 0, stream>>>(x, tables, out);
        fine_plain<14><<<blocks, 256, 0, stream>>>(x, tables, out);
        fine_plain<15><<<blocks, 256, 0, stream>>>(x, tables, out);
    }
}

// Round 12
// 439.962 us; speedup vs baseline: 1.1129x; 1.0107x over previous
//
#include <hip/hip_runtime.h>

#define NPTS   1048576
#define NLEV   16
#define TSIZE  (1u << 19)
#define HMASK  (TSIZE - 1u)
#define NBUCK  32768          // 32^3 Morton buckets

// floor(16 * b^l), b = 32^(1/15): f32-correct values
__device__ __constant__ float NLF_TAB[16] = {
    16.f, 20.f, 25.f, 32.f, 40.f, 50.f, 64.f, 80.f,
    101.f, 128.f, 161.f, 203.f, 256.f, 322.f, 406.f, 512.f};

__device__ __forceinline__ unsigned spread5(unsigned x) {
    x &= 0x1F;
    x = (x | (x << 8)) & 0x100F;
    x = (x | (x << 4)) & 0x10C3;
    x = (x | (x << 2)) & 0x1249;
    return x;
}

__device__ __forceinline__ unsigned morton_key(float u0, float u1, float u2) {
    unsigned k0 = min(31u, (unsigned)(u0 * 32.0f));
    unsigned k1 = min(31u, (unsigned)(u1 * 32.0f));
    unsigned k2 = min(31u, (unsigned)(u2 * 32.0f));
    return (spread5(k0) << 2) | (spread5(k1) << 1) | spread5(k2);
}

__device__ __forceinline__ void uvw(float x0, float x1, float x2,
                                    float* u0, float* u1, float* u2) {
    const float mn = -1.5f, mx = 1.5f, rng = 3.0f;
    *u0 = (fminf(fmaxf(x0, mn), mx) - mn) / rng;
    *u1 = (fminf(fmaxf(x1, mn), mx) - mn) / rng;
    *u2 = (fminf(fmaxf(x2, mn), mx) - mn) / rng;
}

__device__ __forceinline__ void level_lerp(
    float x0, float x1, float x2, float u0, float u1, float u2,
    float Nl, const float2* __restrict__ tab, float* r0, float* r1)
{
#pragma clang fp contract(off)
    const float mn = -1.5f, rng = 3.0f;
    const float box = rng / Nl;

    int g0 = (int)floorf(u0 * Nl);
    int g1 = (int)floorf(u1 * Nl);
    int g2 = (int)floorf(u2 * Nl);

    float vmin0 = (float)g0 * box + mn;
    float vmin1 = (float)g1 * box + mn;
    float vmin2 = (float)g2 * box + mn;

    float den0 = (vmin0 + box) - vmin0;
    float den1 = (vmin1 + box) - vmin1;
    float den2 = (vmin2 + box) - vmin2;

    float wx = (x0 - vmin0) / den0;
    float wy = (x1 - vmin1) / den1;
    float wz = (x2 - vmin2) / den2;

    unsigned hx0 = (unsigned)g0;
    unsigned hx1 = (unsigned)(g0 + 1);
    unsigned hy0 = (unsigned)g1       * 2654435761u;
    unsigned hy1 = (unsigned)(g1 + 1) * 2654435761u;
    unsigned hz0 = (unsigned)g2       * 805459861u;
    unsigned hz1 = (unsigned)(g2 + 1) * 805459861u;

    float2 e000 = tab[(hx0 ^ hy0 ^ hz0) & HMASK];
    float2 e001 = tab[(hx0 ^ hy0 ^ hz1) & HMASK];
    float2 e010 = tab[(hx0 ^ hy1 ^ hz0) & HMASK];
    float2 e011 = tab[(hx0 ^ hy1 ^ hz1) & HMASK];
    float2 e100 = tab[(hx1 ^ hy0 ^ hz0) & HMASK];
    float2 e101 = tab[(hx1 ^ hy0 ^ hz1) & HMASK];
    float2 e110 = tab[(hx1 ^ hy1 ^ hz0) & HMASK];
    float2 e111 = tab[(hx1 ^ hy1 ^ hz1) & HMASK];

    float omx = 1.0f - wx, omy = 1.0f - wy, omz = 1.0f - wz;
    {
        float c00 = e000.x * omx + e100.x * wx;
        float c01 = e001.x * omx + e101.x * wx;
        float c10 = e010.x * omx + e110.x * wx;
        float c11 = e011.x * omx + e111.x * wx;
        float c0  = c00 * omy + c10 * wy;
        float c1  = c01 * omy + c11 * wy;
        *r0 = c0 * omz + c1 * wz;
    }
    {
        float c00 = e000.y * omx + e100.y * wx;
        float c01 = e001.y * omx + e101.y * wx;
        float c10 = e010.y * omx + e110.y * wx;
        float c11 = e011.y * omx + e111.y * wx;
        float c0  = c00 * omy + c10 * wy;
        float c1  = c01 * omy + c11 * wy;
        *r1 = c0 * omz + c1 * wz;
    }
}

// ---------- sort kernels ----------

__global__ __launch_bounds__(1024)
void scan_kernel(unsigned* __restrict__ hist, unsigned* __restrict__ cursor)
{
    __shared__ unsigned part[1024];
    int t = threadIdx.x;
    unsigned local[32];
    unsigned s = 0;
#pragma unroll
    for (int i = 0; i < 32; ++i) { local[i] = hist[t * 32 + i]; s += local[i]; }
    part[t] = s;
    __syncthreads();
    for (int off = 1; off < 1024; off <<= 1) {
        unsigned v = (t >= off) ? part[t - off] : 0;
        __syncthreads();
        part[t] += v;
        __syncthreads();
    }
    unsigned base = (t == 0) ? 0u : part[t - 1];
#pragma unroll
    for (int i = 0; i < 32; ++i) {
        cursor[t * 32 + i] = base;
        base += local[i];
    }
}

__global__ __launch_bounds__(256)
void scatter_kernel(const float* __restrict__ xin,
                    unsigned* __restrict__ cursor,
                    unsigned* __restrict__ sidx,
                    float4* __restrict__ sx4)
{
    int p = blockIdx.x * 256 + threadIdx.x;
    if (p >= NPTS) return;
    float x0 = xin[3 * p], x1 = xin[3 * p + 1], x2 = xin[3 * p + 2];
    float u0, u1, u2; uvw(x0, x1, x2, &u0, &u1, &u2);
    unsigned pos = atomicAdd(&cursor[morton_key(u0, u1, u2)], 1u);
    sidx[pos] = (unsigned)p;
    sx4[pos] = make_float4(x0, x1, x2, 0.0f);
}

// ---------- compute kernels ----------

// Levels 0..7 over sorted points; writes first 64B of each row (full line).
__global__ __launch_bounds__(256)
void coarse_sorted(const unsigned* __restrict__ sidx,
                   const float4* __restrict__ sx4,
                   const float* __restrict__ tables,
                   float* __restrict__ out)
{
#pragma clang fp contract(off)
    int s = blockIdx.x * 256 + threadIdx.x;
    if (s >= NPTS) return;
    unsigned p = sidx[s];
    float4 xv = sx4[s];
    float u0, u1, u2; uvw(xv.x, xv.y, xv.z, &u0, &u1, &u2);

    float res[16];
#pragma unroll
    for (int l = 0; l < 8; ++l) {
        const float2* tab = (const float2*)tables + (size_t)l * TSIZE;
        level_lerp(xv.x, xv.y, xv.z, u0, u1, u2, NLF_TAB[l], tab,
                   &res[2 * l], &res[2 * l + 1]);
    }

    float4* orow = (float4*)(out + (size_t)p * 32);
#pragma unroll
    for (int i = 0; i < 4; ++i)
        orow[i] = make_float4(res[4 * i + 0], res[4 * i + 1],
                              res[4 * i + 2], res[4 * i + 3]);
}

// Levels 8,9 over sorted points; writes one float4 (floats 16..19).
__global__ __launch_bounds__(256)
void mid_sorted(const unsigned* __restrict__ sidx,
                const float4* __restrict__ sx4,
                const float* __restrict__ tables,
                float* __restrict__ out)
{
#pragma clang fp contract(off)
    int s = blockIdx.x * 256 + threadIdx.x;
    if (s >= NPTS) return;
    unsigned p = sidx[s];
    float4 xv = sx4[s];
    float u0, u1, u2; uvw(xv.x, xv.y, xv.z, &u0, &u1, &u2);

    float r[4];
    {
        const float2* tab = (const float2*)tables + (size_t)8 * TSIZE;
        level_lerp(xv.x, xv.y, xv.z, u0, u1, u2, NLF_TAB[8], tab, &r[0], &r[1]);
    }
    {
        const float2* tab = (const float2*)tables + (size_t)9 * TSIZE;
        level_lerp(xv.x, xv.y, xv.z, u0, u1, u2, NLF_TAB[9], tab, &r[2], &r[3]);
    }
    *(float4*)(out + (size_t)p * 32 + 16) = make_float4(r[0], r[1], r[2], r[3]);
}

// All six fine levels (10..15) in ONE dispatch. Blocks 0..4095 -> L15
// (fused Morton hist), 4096..8191 -> L14, ..., 20480..24575 -> L10 (+mask).
// Dispatch order keeps ~one 4MB table L2-resident at a time.
template<bool DO_HIST>
__global__ __launch_bounds__(256)
void fines_merged(const float* __restrict__ xin,
                  const float* __restrict__ tables,
                  float* __restrict__ out,
                  unsigned* __restrict__ hist)
{
#pragma clang fp contract(off)
    int lev = 15 - (int)(blockIdx.x >> 12);            // 4096 blocks per level
    int p   = (int)(blockIdx.x & 4095) * 256 + threadIdx.x;  // < NPTS exactly

    float x0 = xin[3 * p], x1 = xin[3 * p + 1], x2 = xin[3 * p + 2];
    float u0, u1, u2; uvw(x0, x1, x2, &u0, &u1, &u2);

    if (DO_HIST && lev == 15)
        atomicAdd(&hist[morton_key(u0, u1, u2)], 1u);

    const float2* tab = (const float2*)tables + (size_t)lev * TSIZE;
    float r0, r1;
    level_lerp(x0, x1, x2, u0, u1, u2, NLF_TAB[lev], tab, &r0, &r1);
    *(float2*)(out + (size_t)p * 32 + 2 * lev) = make_float2(r0, r1);

    if (lev == 10) {
        const float mn = -1.5f, mx = 1.5f;
        float keep = (x0 >= mn && x0 <= mx &&
                      x1 >= mn && x1 <= mx &&
                      x2 >= mn && x2 <= mx) ? 1.0f : 0.0f;
        out[(size_t)NPTS * 32 + p] = keep;
    }
}

// ---------- fallback (no-workspace path) ----------

__global__ __launch_bounds__(256)
void coarse_kernel(const float* __restrict__ xin,
                   const float* __restrict__ tables,
                   float* __restrict__ out)
{
#pragma clang fp contract(off)
    int p = blockIdx.x * 256 + threadIdx.x;
    if (p >= NPTS) return;
    float x0 = xin[3 * p], x1 = xin[3 * p + 1], x2 = xin[3 * p + 2];
    float u0, u1, u2; uvw(x0, x1, x2, &u0, &u1, &u2);

    float res[16];
#pragma unroll
    for (int l = 0; l < 8; ++l) {
        const float2* tab = (const float2*)tables + (size_t)l * TSIZE;
        level_lerp(x0, x1, x2, u0, u1, u2, NLF_TAB[l], tab,
                   &res[2 * l], &res[2 * l + 1]);
    }
    float4* orow = (float4*)(out + (size_t)p * 32);
#pragma unroll
    for (int i = 0; i < 4; ++i)
        orow[i] = make_float4(res[4 * i + 0], res[4 * i + 1],
                              res[4 * i + 2], res[4 * i + 3]);
}

template<int L>
__global__ __launch_bounds__(256)
void fine_plain(const float* __restrict__ xin,
                const float* __restrict__ tables,
                float* __restrict__ out)
{
#pragma clang fp contract(off)
    int p = blockIdx.x * 256 + threadIdx.x;
    if (p >= NPTS) return;
    float x0 = xin[3 * p], x1 = xin[3 * p + 1], x2 = xin[3 * p + 2];
    float u0, u1, u2; uvw(x0, x1, x2, &u0, &u1, &u2);

    const float2* tab = (const float2*)tables + (size_t)L * TSIZE;
    float r0, r1;
    level_lerp(x0, x1, x2, u0, u1, u2, NLF_TAB[L], tab, &r0, &r1);
    *(float2*)(out + (size_t)p * 32 + 2 * L) = make_float2(r0, r1);
}

extern "C" void kernel_launch(void* const* d_in, const int* in_sizes, int n_in,
                              void* d_out, int out_size, void* d_ws, size_t ws_size,
                              hipStream_t stream) {
    const float* x      = (const float*)d_in[0];
    const float* tables = (const float*)d_in[2];
    float* out = (float*)d_out;

    int n = in_sizes[0] / 3;           // 1048576
    int blocks = (n + 255) / 256;      // 4096

    const size_t HIST_B   = (size_t)NBUCK * 4;              // 128 KB
    const size_t SIDX_OFF = 131072;                         // aligned
    const size_t SX4_OFF  = SIDX_OFF + (size_t)NPTS * 4;    // +4 MB
    const size_t NEEDED   = SX4_OFF + (size_t)NPTS * 16;    // ≈ 20.2 MB

    if (ws_size >= NEEDED) {
        unsigned* hist = (unsigned*)d_ws;
        unsigned* sidx = (unsigned*)((char*)d_ws + SIDX_OFF);
        float4*   sx4  = (float4*)((char*)d_ws + SX4_OFF);

        hipMemsetAsync(hist, 0, HIST_B, stream);

        // All fine levels in one dispatch; L15 sub-grid builds the histogram.
        fines_merged<true><<<6 * blocks, 256, 0, stream>>>(x, tables, out, hist);

        scan_kernel<<<1, 1024, 0, stream>>>(hist, hist);  // in-place -> cursors
        scatter_kernel<<<blocks, 256, 0, stream>>>(x, hist, sidx, sx4);
        coarse_sorted<<<blocks, 256, 0, stream>>>(sidx, sx4, tables, out);
        mid_sorted<<<blocks, 256, 0, stream>>>(sidx, sx4, tables, out);
    } else {
        coarse_kernel<<<blocks, 256, 0, stream>>>(x, tables, out);
        fine_plain< 8><<<blocks, 256, 0, stream>>>(x, tables, out);
        fine_plain< 9><<<blocks, 256, 0, stream>>>(x, tables, out);
        fines_merged<false><<<6 * blocks, 256, 0, stream>>>(x, tables, out, nullptr);
    }
}